// Round 7
// baseline (589.527 us; speedup 1.0000x reference)
//
#include <hip/hip_runtime.h>
#include <hip/hip_bf16.h>

typedef __hip_bfloat16 bf16;
typedef short bf16x8 __attribute__((ext_vector_type(8)));
typedef short short4v __attribute__((ext_vector_type(4)));
typedef float f32x4 __attribute__((ext_vector_type(4)));

struct __attribute__((packed, aligned(4))) uf4 { f32x4 v; };
struct __attribute__((packed, aligned(4))) uu4 { uint4 v; };

constexpr int C  = 192;
constexpr int HF = 128;
constexpr int L  = 4096;          // 64*64
constexpr size_t SLL = (size_t)L * L;

__device__ inline float u2f(unsigned u){
    union { unsigned u; float f; } x; x.u = u; return x.f;
}
__device__ inline short f2bf_s(float f){
    bf16 h = __float2bfloat16(f);
    return *reinterpret_cast<short*>(&h);
}
__device__ inline unsigned f2bf_u(float f){
    bf16 h = __float2bfloat16(f);
    return (unsigned)(*reinterpret_cast<unsigned short*>(&h));
}

// ---------------- prep: downsample, bf16 split, parity images, ss ----------------
__global__ void prep_kernel(const float* __restrict__ f, const float* __restrict__ b,
                            bf16* __restrict__ fdh, bf16* __restrict__ fdl,
                            bf16* __restrict__ bdh, bf16* __restrict__ bdl,
                            bf16* __restrict__ bpar, float* __restrict__ ss, int batch){
    int pos = blockIdx.x;            // p*64+q
    int p = pos >> 6, q = pos & 63;
    int c = threadIdx.x;             // 0..191
    const float* fb = f + (size_t)batch * HF * HF * C;
    const float* bb = b + (size_t)batch * HF * HF * C;

    float fv = fb[((2*p)*HF + 2*q)*C + c];
    bf16 fh = __float2bfloat16(fv);
    fdh[(size_t)pos*C + c] = fh;
    fdl[(size_t)pos*C + c] = __float2bfloat16(fv - __bfloat162float(fh));

    float b00 = 0.f;
    #pragma unroll
    for (int dx = 0; dx < 2; dx++)
      #pragma unroll
      for (int dy = 0; dy < 2; dy++){
        float bv = bb[((2*p+dx)*HF + (2*q+dy))*C + c];
        int par = dx*2 + dy;
        bpar[((size_t)par*L + pos)*C + c] = __float2bfloat16(bv);   // [par][k=p*64+q][c]
        if (par == 0){
            b00 = bv;
            bf16 bh = __float2bfloat16(bv);
            bdh[(size_t)pos*C + c] = bh;
            bdl[(size_t)pos*C + c] = __float2bfloat16(bv - __bfloat162float(bh));
        }
      }

    __shared__ float red[3];
    float v = b00 * b00;
    #pragma unroll
    for (int o = 32; o > 0; o >>= 1) v += __shfl_down(v, o);
    if ((threadIdx.x & 63) == 0) red[threadIdx.x >> 6] = v;
    __syncthreads();
    if (threadIdx.x == 0) ss[pos] = red[0] + red[1] + red[2];
}

// ---------------- norm (3x3 window of ss) and mask mm ----------------------------
__global__ void normmm_kernel(const float* __restrict__ mask, const float* __restrict__ ss,
                              float* __restrict__ rnorm, float* __restrict__ mmv){
    int pos = blockIdx.x*256 + threadIdx.x;
    int p = pos >> 6, q = pos & 63;
    float s = 0.f, ms = 0.f;
    #pragma unroll
    for (int di = -1; di <= 1; di++)
      #pragma unroll
      for (int dj = -1; dj <= 1; dj++){
        int pp = p + di, qq = q + dj;
        if ((unsigned)pp < 64u && (unsigned)qq < 64u){
            s  += ss[pp*64 + qq];
            ms += mask[(2*pp)*HF + 2*qq];
        }
      }
    float n = fmaxf(sqrtf(s), 1e-4f);
    rnorm[pos] = 1.f / n;
    mmv[pos] = (ms == 0.f) ? 1.f : 0.f;
}

// ---------------- repack bpar[par][k][c] -> bparT[par][c][k] ---------------------
__global__ void repack_kernel(const bf16* __restrict__ bpar, bf16* __restrict__ bparT){
    __shared__ bf16 lds[64][66];
    int c0 = blockIdx.x * 64;
    int k0 = blockIdx.y * 64;
    int par = blockIdx.z;
    const bf16* src = bpar + (size_t)par*L*C;
    bf16* dst = bparT + (size_t)par*C*L;
    int t = threadIdx.x;
    #pragma unroll
    for (int it = 0; it < 16; it++){
        int e = t + it*256; int cc = e & 63, kk = e >> 6;
        lds[kk][cc] = src[(size_t)(k0+kk)*C + c0 + cc];
    }
    __syncthreads();
    #pragma unroll
    for (int it = 0; it < 16; it++){
        int e = t + it*256; int kk = e & 63, cc = e >> 6;
        dst[(size_t)(c0+cc)*L + k0 + kk] = lds[kk][cc];
    }
}

// ---------------- Gram GEMM: G[a,b] = sum_c fd[a,c]*bd[b,c], split-bf16 ----------
__global__ __launch_bounds__(256) void gemm_g(
        const bf16* __restrict__ fdh, const bf16* __restrict__ fdl,
        const bf16* __restrict__ bdh, const bf16* __restrict__ bdl,
        float* __restrict__ G){
    __shared__ __align__(16) bf16 Ah[128][40], Al[128][40], Bh[128][40], Bl[128][40];
    int t = threadIdx.x;
    int m0 = blockIdx.y * 128, n0 = blockIdx.x * 128;
    int wv = t >> 6, lane = t & 63, lr = lane & 15, lq = lane >> 4;
    int wm = (wv >> 1) * 64, wn = (wv & 1) * 64;
    f32x4 acc[4][4] = {};

    for (int kk = 0; kk < 6; kk++){
        int k0 = kk * 32;
        __syncthreads();
        #pragma unroll
        for (int r = 0; r < 2; r++){
            int e = r*256 + t; int row = e >> 2, kc = e & 3;
            *(uint4*)&Ah[row][kc*8] = *(const uint4*)(fdh + (size_t)(m0+row)*C + k0 + kc*8);
            *(uint4*)&Al[row][kc*8] = *(const uint4*)(fdl + (size_t)(m0+row)*C + k0 + kc*8);
            *(uint4*)&Bh[row][kc*8] = *(const uint4*)(bdh + (size_t)(n0+row)*C + k0 + kc*8);
            *(uint4*)&Bl[row][kc*8] = *(const uint4*)(bdl + (size_t)(n0+row)*C + k0 + kc*8);
        }
        __syncthreads();
        bf16x8 ah[4], al[4], bh[4], bl[4];
        #pragma unroll
        for (int mt = 0; mt < 4; mt++){
            ah[mt] = *(bf16x8*)&Ah[wm + mt*16 + lr][lq*8];
            al[mt] = *(bf16x8*)&Al[wm + mt*16 + lr][lq*8];
        }
        #pragma unroll
        for (int nt = 0; nt < 4; nt++){
            bh[nt] = *(bf16x8*)&Bh[wn + nt*16 + lr][lq*8];
            bl[nt] = *(bf16x8*)&Bl[wn + nt*16 + lr][lq*8];
        }
        #pragma unroll
        for (int mt = 0; mt < 4; mt++)
          #pragma unroll
          for (int nt = 0; nt < 4; nt++){
            acc[mt][nt] = __builtin_amdgcn_mfma_f32_16x16x32_bf16(ah[mt], bh[nt], acc[mt][nt], 0,0,0);
            acc[mt][nt] = __builtin_amdgcn_mfma_f32_16x16x32_bf16(ah[mt], bl[nt], acc[mt][nt], 0,0,0);
            acc[mt][nt] = __builtin_amdgcn_mfma_f32_16x16x32_bf16(al[mt], bh[nt], acc[mt][nt], 0,0,0);
          }
    }
    #pragma unroll
    for (int mt = 0; mt < 4; mt++)
      #pragma unroll
      for (int nt = 0; nt < 4; nt++)
        #pragma unroll
        for (int r = 0; r < 4; r++){
            int gr = m0 + wm + mt*16 + lq*4 + r;
            int gc = n0 + wn + nt*16 + lr;
            G[(size_t)gr*L + gc] = acc[mt][nt][r];
        }
}

// ------- fused s1 (9-tap) + fuse1 (3-tap diag), LDS-staged G tile ---------------
// Block: 8 A-rows x 256 B-cols. LDS holds 3 di-groups x 12 rows x 272 cols of G,
// each group's storage pre-shifted by 64*(di-1) so tap col = c8 + c + 4 for all di.
__global__ __launch_bounds__(256) void s1f_kernel(const float* __restrict__ G,
                                                  const float* __restrict__ rnorm,
                                                  float* __restrict__ F1){
    __shared__ float lg[3][12][272];
    int t = threadIdx.x;
    int b0 = blockIdx.x * 256;
    int a0 = blockIdx.y * 8;

    // stage-in: 3*12*68 = 2448 uint4 loads, coalesced
    #pragma unroll
    for (int i = 0; i < 10; i++){
        int idx = t + i*256;
        if (idx < 2448){
            int g = idx / 816;
            int rem = idx - g*816;
            int row = rem / 68;
            int xc = (rem - row*68) * 4;
            const float* src = G + (size_t)(a0 + 64*(g-1) + row - 2)*L
                                 + (b0 + 64*(g-1) - 4 + xc);
            *(f32x4*)&lg[g][row][xc] = ((const uf4*)src)->v;
        }
    }
    __syncthreads();

    int k  = t >> 5;            // 0..7 : output row within tile
    int c8 = (t & 31) * 8;      // 0..248 : col offset within tile
    int A  = a0 + k;
    int tB0 = b0 + c8;

    bool fvA[3]; bool rowOK[3][3]; bool colOK[3][3];
    #pragma unroll
    for (int dd = 0; dd < 3; dd++){
        int A1 = A + dd - 1;
        fvA[dd] = (unsigned)A1 < (unsigned)L;
        int i1 = A1 >> 6, j1 = A1 & 63;
        #pragma unroll
        for (int kk = 0; kk < 3; kk++){
            rowOK[dd][kk] = (unsigned)(i1 + kk - 1) < 64u;
            colOK[dd][kk] = (unsigned)(j1 + kk - 1) < 64u;
        }
    }

    float S[3][8];
    #pragma unroll
    for (int dd = 0; dd < 3; dd++)
      #pragma unroll
      for (int e = 0; e < 8; e++) S[dd][e] = 0.f;

    #pragma unroll
    for (int di = 0; di < 3; di++){
        float gg[5][8];
        #pragma unroll
        for (int s = 0; s < 5; s++){
            const float* p = &lg[di][k + s][c8 + s + 2];
            #pragma unroll
            for (int e = 0; e < 8; e++) gg[s][e] = p[e];
        }
        #pragma unroll
        for (int dd = 0; dd < 3; dd++){
            const int d = dd - 1;
            #pragma unroll
            for (int e = 0; e < 8; e++){
                int B1 = tB0 + e + d;
                int p1 = B1 >> 6, q1 = B1 & 63;
                bool rm = rowOK[dd][di] && ((unsigned)(p1 + di - 1) < 64u);
                float r = 0.f;
                #pragma unroll
                for (int dj = 0; dj < 3; dj++){
                    bool cm = colOK[dd][dj] && ((unsigned)(q1 + dj - 1) < 64u);
                    r += cm ? gg[d + dj + 1][e] : 0.f;
                }
                S[dd][e] += rm ? r : 0.f;
            }
        }
    }

    float rn[12];
    const float* rp = rnorm + tB0 - 2;
    *(f32x4*)&rn[0] = ((const uf4*)rp)->v;
    *(f32x4*)&rn[4] = ((const uf4*)(rp+4))->v;
    *(f32x4*)&rn[8] = ((const uf4*)(rp+8))->v;

    float acc[8];
    #pragma unroll
    for (int e = 0; e < 8; e++){
        float a = 0.f;
        #pragma unroll
        for (int dd = 0; dd < 3; dd++){
            const int d = dd - 1;
            int B1 = tB0 + e + d;
            bool ok = fvA[dd] && ((unsigned)B1 < (unsigned)L);
            float wd = ok ? rn[e + d + 2] : 0.f;
            a += wd * S[dd][e];
        }
        acc[e] = a;
    }
    float* o = F1 + (size_t)A*L + tB0;
    *(f32x4*)(o)     = *(f32x4*)&acc[0];
    *(f32x4*)(o + 4) = *(f32x4*)&acc[4];
}

// -------- fuse2 (3-tap, transposed-flat wrap) + mask + softmax, vectorized -------
__global__ __launch_bounds__(256) void fsoft_kernel(const float* __restrict__ F1,
                                                    const float* __restrict__ mmv,
                                                    bf16* __restrict__ attn){
    int A = blockIdx.x, t = threadIdx.x;
    int i = A >> 6, j = A & 63;
    bool pok = A < L-1, mok = A > 0;
    int rowp = (i < 63) ? A + 64 : j + 1;
    int rowm = (i > 0)  ? A - 64 : 63*64 + j - 1;
    const float* FA = F1 + (size_t)A*L;
    const float* FP = F1 + (size_t)rowp*L;
    const float* FM = F1 + (size_t)rowm*L;

    float z[16]; float mx = -1e30f;
    #pragma unroll
    for (int it = 0; it < 4; it++){
        int b0 = (it*256 + t)*4;
        int p = b0 >> 6, q0 = b0 & 63;
        f32x4 v  = *(const f32x4*)(FA + b0);
        f32x4 mv = *(const f32x4*)(mmv + b0);
        f32x4 tp, tm;
        if (p < 63) tp = ((const uf4*)(FP + b0 + 64))->v;
        else        tp = ((const uf4*)(FP + q0 + 1))->v;
        if (p > 0)  tm = ((const uf4*)(FM + b0 - 64))->v;
        else        tm = ((const uf4*)(FM + 63*64 + q0 - 1))->v;
        #pragma unroll
        for (int e = 0; e < 4; e++){
            int Bq = b0 + e;
            float val = v[e];
            if (pok && Bq < L-1) val += tp[e];
            if (mok && Bq > 0)   val += tm[e];
            val = val * mv[e] * 10.f;
            z[it*4+e] = val; mx = fmaxf(mx, val);
        }
    }
    __shared__ float red[4];
    #pragma unroll
    for (int o = 32; o > 0; o >>= 1) mx = fmaxf(mx, __shfl_down(mx, o));
    if ((t & 63) == 0) red[t >> 6] = mx;
    __syncthreads();
    mx = fmaxf(fmaxf(red[0], red[1]), fmaxf(red[2], red[3]));
    float sm = 0.f;
    #pragma unroll
    for (int it = 0; it < 16; it++){ z[it] = __expf(z[it] - mx); sm += z[it]; }
    #pragma unroll
    for (int o = 32; o > 0; o >>= 1) sm += __shfl_down(sm, o);
    __syncthreads();
    if ((t & 63) == 0) red[t >> 6] = sm;
    __syncthreads();
    sm = red[0] + red[1] + red[2] + red[3];
    float inv = 1.f / sm;
    bf16* aA = attn + (size_t)A*L;
    #pragma unroll
    for (int it = 0; it < 4; it++){
        int b0 = (it*256 + t)*4;
        f32x4 mv = *(const f32x4*)(mmv + b0);
        short sv[4];
        #pragma unroll
        for (int e = 0; e < 4; e++)
            sv[e] = f2bf_s(z[it*4+e] * inv * mv[e]);
        *(short4v*)(aA + b0) = *(short4v*)&sv[0];
    }
}

// ---------------- v4: materialize 4 parity V matrices, 9 shared tap-rows ---------
__global__ __launch_bounds__(256) void v4_kernel(const bf16* __restrict__ attn,
                                                 bf16* __restrict__ V4){
    int t = threadIdx.x;
    int k0 = (blockIdx.x*256 + t)*8;
    int m  = blockIdx.y;
    int X = m >> 6, Yv = m & 63, P = k0 >> 6, Q0 = k0 & 63;

    const int del[9] = {0, 64, -64, 1, -1, 65, 63, -65, -63};
    float e8[9][8];
    #pragma unroll
    for (int r = 0; r < 9; r++){
        const int d = del[r];
        const bf16* base = attn + (size_t)(m - d)*L + (k0 - d);
        if ((d & 1) == 0){
            uint w[4];
            *(uint4*)w = ((const uu4*)base)->v;
            #pragma unroll
            for (int j = 0; j < 8; j++)
                e8[r][j] = u2f((j & 1) ? (w[j>>1] & 0xffff0000u) : (w[j>>1] << 16));
        } else {
            uint w[5];
            *(uint4*)w = ((const uu4*)(base - 1))->v;
            w[4] = *(const uint*)(base + 7);
            #pragma unroll
            for (int j = 0; j < 8; j++){
                int h = j + 1;
                e8[r][j] = u2f((h & 1) ? (w[h>>1] & 0xffff0000u) : (w[h>>1] << 16));
            }
        }
    }

    #pragma unroll
    for (int par = 0; par < 4; par++){
        const int sx = 1 - 2*(par >> 1), sy = 1 - 2*(par & 1);
        const int i2 = (sx > 0) ? 1 : 2;
        const int i3 = (sy > 0) ? 3 : 4;
        const int i4 = (sx > 0) ? ((sy > 0) ? 5 : 6) : ((sy > 0) ? 8 : 7);
        bool c2 = (unsigned)(P - sx) < 64u;
        bool m2 = ((unsigned)(X - sx) < 64u) && c2;
        bool r3 = (unsigned)(Yv - sy) < 64u;
        bool m4 = m2 && r3;
        uint ow[4];
        #pragma unroll
        for (int w = 0; w < 4; w++){
            float vv[2];
            #pragma unroll
            for (int h = 0; h < 2; h++){
                int j = 2*w + h;
                bool qk = (unsigned)(Q0 + j - sy) < 64u;
                float v = e8[0][j]
                        + (m2 ? e8[i2][j] : 0.f)
                        + ((r3 && qk) ? e8[i3][j] : 0.f)
                        + ((m4 && qk) ? e8[i4][j] : 0.f);
                vv[h] = v;
            }
            ow[w] = f2bf_u(vv[0]) | (f2bf_u(vv[1]) << 16);
        }
        *(uint4*)(V4 + (size_t)par*SLL + (size_t)m*L + k0) = *(uint4*)ow;
    }
}

// ---------------- paste GEMM: out = 0.25 * V4_par @ bparT_par^T ------------------
// R2-measured structure: M64 tile, single-buffered, grid (64,4) = 1 block/CU.
__global__ __launch_bounds__(256) void gemm_paste(
        const bf16* __restrict__ V4, const bf16* __restrict__ bparT,
        float* __restrict__ out, int batch){
    __shared__ __align__(16) bf16 Ab[64][72];
    __shared__ __align__(16) bf16 Bb[192][72];
    int t = threadIdx.x;
    int par = blockIdx.y;
    int m0 = blockIdx.x * 64;
    const bf16* Am = V4    + (size_t)par*SLL;
    const bf16* Bm = bparT + (size_t)par*C*L;
    int wv = t >> 6, lane = t & 63, lr = lane & 15, lq = lane >> 4;
    f32x4 acc[4][3] = {};

    for (int kk = 0; kk < 64; kk++){
        int k0 = kk * 64;
        __syncthreads();
        #pragma unroll
        for (int r = 0; r < 2; r++){
            int e = r*256 + t; int row = e >> 3, kc = e & 7;
            *(uint4*)&Ab[row][kc*8] = *(const uint4*)(Am + (size_t)(m0+row)*L + k0 + kc*8);
        }
        #pragma unroll
        for (int r = 0; r < 6; r++){
            int e = r*256 + t; int c2 = e >> 3, kc = e & 7;
            *(uint4*)&Bb[c2][kc*8] = *(const uint4*)(Bm + (size_t)c2*L + k0 + kc*8);
        }
        __syncthreads();
        #pragma unroll
        for (int kk2 = 0; kk2 < 2; kk2++){
            bf16x8 a[4], bfr[3];
            #pragma unroll
            for (int mt = 0; mt < 4; mt++)
                a[mt] = *(bf16x8*)&Ab[mt*16 + lr][kk2*32 + lq*8];
            #pragma unroll
            for (int nt = 0; nt < 3; nt++)
                bfr[nt] = *(bf16x8*)&Bb[wv*48 + nt*16 + lr][kk2*32 + lq*8];
            #pragma unroll
            for (int mt = 0; mt < 4; mt++)
              #pragma unroll
              for (int nt = 0; nt < 3; nt++)
                acc[mt][nt] = __builtin_amdgcn_mfma_f32_16x16x32_bf16(a[mt], bfr[nt], acc[mt][nt], 0,0,0);
        }
    }
    #pragma unroll
    for (int mt = 0; mt < 4; mt++)
      #pragma unroll
      for (int nt = 0; nt < 3; nt++)
        #pragma unroll
        for (int r = 0; r < 4; r++){
            int m = m0 + mt*16 + lq*4 + r;
            int X = m >> 6, Yv = m & 63;
            int dx = par >> 1, dy = par & 1;
            int x = 2*X + dx, y = 2*Yv + dy, c2 = wv*48 + nt*16 + lr;
            out[(size_t)((batch*HF + x)*HF + y)*C + c2] = 0.25f * acc[mt][nt][r];
        }
}

// ---------------- host ----------------
extern "C" void kernel_launch(void* const* d_in, const int* in_sizes, int n_in,
                              void* d_out, int out_size, void* d_ws, size_t ws_size,
                              hipStream_t stream){
    const float* f    = (const float*)d_in[0];
    const float* b    = (const float*)d_in[1];
    const float* mask = (const float*)d_in[2];
    float* out = (float*)d_out;
    char* ws = (char*)d_ws;

    constexpr size_t off_G     = 1179648ull;               // 64 MB, 1.125 MB guards
    constexpr size_t off_F1    = 69468160ull;              // 64 MB
    constexpr size_t off_attn  = 137232384ull;             // 32 MB, ~640 KB guards
    constexpr size_t off_bparT = 171442176ull;             // 6.29 MB
    constexpr size_t off_ss    = 177733632ull;
    constexpr size_t off_rn    = 177750016ull;
    constexpr size_t off_mmv   = 177766656ull;

    float* G    = (float*)(ws + off_G);
    float* F1   = (float*)(ws + off_F1);
    bf16*  attn = (bf16*) (ws + off_attn);
    bf16*  V4   = (bf16*) (ws);                            // 128 MB, overlays G+F1 (dead)
    bf16*  bpar = (bf16*) (ws + off_F1);                   // alias: dead before F1 written
    bf16*  fdh  = (bf16*) (ws + off_attn);                 // alias: dead before attn written
    bf16*  fdl  = (bf16*) (ws + off_attn + 1572864ull);
    bf16*  bdh  = (bf16*) (ws + off_attn + 3145728ull);
    bf16*  bdl  = (bf16*) (ws + off_attn + 4718592ull);
    bf16*  bparT= (bf16*) (ws + off_bparT);
    float* ss    = (float*)(ws + off_ss);
    float* rnorm = (float*)(ws + off_rn) + 16;
    float* mmv   = (float*)(ws + off_mmv);

    for (int batch = 0; batch < 2; batch++){
        prep_kernel  <<<dim3(4096),    dim3(192), 0, stream>>>(f, b, fdh, fdl, bdh, bdl, bpar, ss, batch);
        normmm_kernel<<<dim3(16),      dim3(256), 0, stream>>>(mask, ss, rnorm, mmv);
        repack_kernel<<<dim3(3,64,4),  dim3(256), 0, stream>>>(bpar, bparT);
        gemm_g       <<<dim3(32,32),   dim3(256), 0, stream>>>(fdh, fdl, bdh, bdl, G);
        s1f_kernel   <<<dim3(16,512),  dim3(256), 0, stream>>>(G, rnorm, F1);
        fsoft_kernel <<<dim3(4096),    dim3(256), 0, stream>>>(F1, mmv, attn);
        v4_kernel    <<<dim3(2,4096),  dim3(256), 0, stream>>>(attn, V4);
        gemm_paste   <<<dim3(64,4),    dim3(256), 0, stream>>>(V4, bparT, out, batch);
    }
}

// Round 8
// 544.738 us; speedup vs baseline: 1.0822x; 1.0822x over previous
//
#include <hip/hip_runtime.h>
#include <hip/hip_bf16.h>

typedef __hip_bfloat16 bf16;
typedef short bf16x8 __attribute__((ext_vector_type(8)));
typedef short short4v __attribute__((ext_vector_type(4)));
typedef float f32x4 __attribute__((ext_vector_type(4)));

struct __attribute__((packed, aligned(4))) uf4 { f32x4 v; };
struct __attribute__((packed, aligned(4))) uu4 { uint4 v; };

constexpr int C  = 192;
constexpr int HF = 128;
constexpr int L  = 4096;          // 64*64
constexpr size_t SLL = (size_t)L * L;

__device__ inline float u2f(unsigned u){
    union { unsigned u; float f; } x; x.u = u; return x.f;
}
__device__ inline short f2bf_s(float f){
    bf16 h = __float2bfloat16(f);
    return *reinterpret_cast<short*>(&h);
}
__device__ inline unsigned f2bf_u(float f){
    bf16 h = __float2bfloat16(f);
    return (unsigned)(*reinterpret_cast<unsigned short*>(&h));
}

// ---------------- prep: downsample, bf16 split, parity images, ss ----------------
__global__ void prep_kernel(const float* __restrict__ f, const float* __restrict__ b,
                            bf16* __restrict__ fdh, bf16* __restrict__ fdl,
                            bf16* __restrict__ bdh, bf16* __restrict__ bdl,
                            bf16* __restrict__ bpar, float* __restrict__ ss, int batch){
    int pos = blockIdx.x;            // p*64+q
    int p = pos >> 6, q = pos & 63;
    int c = threadIdx.x;             // 0..191
    const float* fb = f + (size_t)batch * HF * HF * C;
    const float* bb = b + (size_t)batch * HF * HF * C;

    float fv = fb[((2*p)*HF + 2*q)*C + c];
    bf16 fh = __float2bfloat16(fv);
    fdh[(size_t)pos*C + c] = fh;
    fdl[(size_t)pos*C + c] = __float2bfloat16(fv - __bfloat162float(fh));

    float b00 = 0.f;
    #pragma unroll
    for (int dx = 0; dx < 2; dx++)
      #pragma unroll
      for (int dy = 0; dy < 2; dy++){
        float bv = bb[((2*p+dx)*HF + (2*q+dy))*C + c];
        int par = dx*2 + dy;
        bpar[((size_t)par*L + pos)*C + c] = __float2bfloat16(bv);   // [par][k=p*64+q][c]
        if (par == 0){
            b00 = bv;
            bf16 bh = __float2bfloat16(bv);
            bdh[(size_t)pos*C + c] = bh;
            bdl[(size_t)pos*C + c] = __float2bfloat16(bv - __bfloat162float(bh));
        }
      }

    __shared__ float red[3];
    float v = b00 * b00;
    #pragma unroll
    for (int o = 32; o > 0; o >>= 1) v += __shfl_down(v, o);
    if ((threadIdx.x & 63) == 0) red[threadIdx.x >> 6] = v;
    __syncthreads();
    if (threadIdx.x == 0) ss[pos] = red[0] + red[1] + red[2];
}

// ---------------- norm (3x3 window of ss) and mask mm ----------------------------
__global__ void normmm_kernel(const float* __restrict__ mask, const float* __restrict__ ss,
                              float* __restrict__ rnorm, float* __restrict__ mmv){
    int pos = blockIdx.x*256 + threadIdx.x;
    int p = pos >> 6, q = pos & 63;
    float s = 0.f, ms = 0.f;
    #pragma unroll
    for (int di = -1; di <= 1; di++)
      #pragma unroll
      for (int dj = -1; dj <= 1; dj++){
        int pp = p + di, qq = q + dj;
        if ((unsigned)pp < 64u && (unsigned)qq < 64u){
            s  += ss[pp*64 + qq];
            ms += mask[(2*pp)*HF + 2*qq];
        }
      }
    float n = fmaxf(sqrtf(s), 1e-4f);
    rnorm[pos] = 1.f / n;
    mmv[pos] = (ms == 0.f) ? 1.f : 0.f;
}

// ---------------- repack bpar[par][k][c] -> bparT[par][c][k] ---------------------
__global__ void repack_kernel(const bf16* __restrict__ bpar, bf16* __restrict__ bparT){
    __shared__ bf16 lds[64][66];
    int c0 = blockIdx.x * 64;
    int k0 = blockIdx.y * 64;
    int par = blockIdx.z;
    const bf16* src = bpar + (size_t)par*L*C;
    bf16* dst = bparT + (size_t)par*C*L;
    int t = threadIdx.x;
    #pragma unroll
    for (int it = 0; it < 16; it++){
        int e = t + it*256; int cc = e & 63, kk = e >> 6;
        lds[kk][cc] = src[(size_t)(k0+kk)*C + c0 + cc];
    }
    __syncthreads();
    #pragma unroll
    for (int it = 0; it < 16; it++){
        int e = t + it*256; int kk = e & 63, cc = e >> 6;
        dst[(size_t)(c0+cc)*L + k0 + kk] = lds[kk][cc];
    }
}

// ---------------- Gram GEMM: G[a,b] = sum_c fd[a,c]*bd[b,c], split-bf16 ----------
__global__ __launch_bounds__(256) void gemm_g(
        const bf16* __restrict__ fdh, const bf16* __restrict__ fdl,
        const bf16* __restrict__ bdh, const bf16* __restrict__ bdl,
        float* __restrict__ G){
    __shared__ __align__(16) bf16 Ah[128][40], Al[128][40], Bh[128][40], Bl[128][40];
    int t = threadIdx.x;
    int m0 = blockIdx.y * 128, n0 = blockIdx.x * 128;
    int wv = t >> 6, lane = t & 63, lr = lane & 15, lq = lane >> 4;
    int wm = (wv >> 1) * 64, wn = (wv & 1) * 64;
    f32x4 acc[4][4] = {};

    for (int kk = 0; kk < 6; kk++){
        int k0 = kk * 32;
        __syncthreads();
        #pragma unroll
        for (int r = 0; r < 2; r++){
            int e = r*256 + t; int row = e >> 2, kc = e & 3;
            *(uint4*)&Ah[row][kc*8] = *(const uint4*)(fdh + (size_t)(m0+row)*C + k0 + kc*8);
            *(uint4*)&Al[row][kc*8] = *(const uint4*)(fdl + (size_t)(m0+row)*C + k0 + kc*8);
            *(uint4*)&Bh[row][kc*8] = *(const uint4*)(bdh + (size_t)(n0+row)*C + k0 + kc*8);
            *(uint4*)&Bl[row][kc*8] = *(const uint4*)(bdl + (size_t)(n0+row)*C + k0 + kc*8);
        }
        __syncthreads();
        bf16x8 ah[4], al[4], bh[4], bl[4];
        #pragma unroll
        for (int mt = 0; mt < 4; mt++){
            ah[mt] = *(bf16x8*)&Ah[wm + mt*16 + lr][lq*8];
            al[mt] = *(bf16x8*)&Al[wm + mt*16 + lr][lq*8];
        }
        #pragma unroll
        for (int nt = 0; nt < 4; nt++){
            bh[nt] = *(bf16x8*)&Bh[wn + nt*16 + lr][lq*8];
            bl[nt] = *(bf16x8*)&Bl[wn + nt*16 + lr][lq*8];
        }
        #pragma unroll
        for (int mt = 0; mt < 4; mt++)
          #pragma unroll
          for (int nt = 0; nt < 4; nt++){
            acc[mt][nt] = __builtin_amdgcn_mfma_f32_16x16x32_bf16(ah[mt], bh[nt], acc[mt][nt], 0,0,0);
            acc[mt][nt] = __builtin_amdgcn_mfma_f32_16x16x32_bf16(ah[mt], bl[nt], acc[mt][nt], 0,0,0);
            acc[mt][nt] = __builtin_amdgcn_mfma_f32_16x16x32_bf16(al[mt], bh[nt], acc[mt][nt], 0,0,0);
          }
    }
    #pragma unroll
    for (int mt = 0; mt < 4; mt++)
      #pragma unroll
      for (int nt = 0; nt < 4; nt++)
        #pragma unroll
        for (int r = 0; r < 4; r++){
            int gr = m0 + wm + mt*16 + lq*4 + r;
            int gc = n0 + wn + nt*16 + lr;
            G[(size_t)gr*L + gc] = acc[mt][nt][r];
        }
}

// ------- fused s1 (9-tap) + fuse1 (3-tap diag), LDS-staged G, conflict-free ------
// Block: 8 A-rows x 256 B-cols. Thread t handles row (t>>5), cols c1+32*e
// (c1 = t&31) -> all LDS tap reads are lane-stride-1 = conflict-free.
__global__ __launch_bounds__(256) void s1f_kernel(const float* __restrict__ G,
                                                  const float* __restrict__ rnorm,
                                                  float* __restrict__ F1){
    __shared__ float lg[3][12][272];
    __shared__ float rl[264];
    int t = threadIdx.x;
    int b0 = blockIdx.x * 256;
    int a0 = blockIdx.y * 8;

    // stage-in G: 3*12*68 = 2448 uint4 loads, coalesced
    #pragma unroll
    for (int i = 0; i < 10; i++){
        int idx = t + i*256;
        if (idx < 2448){
            int g = idx / 816;
            int rem = idx - g*816;
            int row = rem / 68;
            int xc = (rem - row*68) * 4;
            const float* src = G + (size_t)(a0 + 64*(g-1) + row - 2)*L
                                 + (b0 + 64*(g-1) - 4 + xc);
            *(f32x4*)&lg[g][row][xc] = ((const uf4*)src)->v;
        }
    }
    // stage rnorm segment [b0-1 .. b0+256]
    for (int i = t; i < 258; i += 256) rl[i] = rnorm[b0 - 1 + i];
    __syncthreads();

    int k  = t >> 5;            // 0..7 : output row within tile
    int c1 = t & 31;            // 0..31 : base col (stride-32 outputs)
    int A  = a0 + k;

    bool fvA[3]; bool rowOK[3][3]; bool colOK[3][3];
    #pragma unroll
    for (int dd = 0; dd < 3; dd++){
        int A1 = A + dd - 1;
        fvA[dd] = (unsigned)A1 < (unsigned)L;
        int i1 = A1 >> 6, j1 = A1 & 63;
        #pragma unroll
        for (int kk = 0; kk < 3; kk++){
            rowOK[dd][kk] = (unsigned)(i1 + kk - 1) < 64u;
            colOK[dd][kk] = (unsigned)(j1 + kk - 1) < 64u;
        }
    }

    float S[3][8];
    #pragma unroll
    for (int dd = 0; dd < 3; dd++)
      #pragma unroll
      for (int e = 0; e < 8; e++) S[dd][e] = 0.f;

    #pragma unroll
    for (int di = 0; di < 3; di++){
        float gg[5][8];
        #pragma unroll
        for (int s = 0; s < 5; s++)
          #pragma unroll
          for (int e = 0; e < 8; e++)
            gg[s][e] = lg[di][k + s][c1 + 32*e + s + 2];
        #pragma unroll
        for (int dd = 0; dd < 3; dd++){
            const int d = dd - 1;
            #pragma unroll
            for (int e = 0; e < 8; e++){
                int B1 = b0 + c1 + 32*e + d;
                int p1 = B1 >> 6, q1 = B1 & 63;
                bool rm = rowOK[dd][di] && ((unsigned)(p1 + di - 1) < 64u);
                float r = 0.f;
                #pragma unroll
                for (int dj = 0; dj < 3; dj++){
                    bool cm = colOK[dd][dj] && ((unsigned)(q1 + dj - 1) < 64u);
                    r += cm ? gg[d + dj + 1][e] : 0.f;
                }
                S[dd][e] += rm ? r : 0.f;
            }
        }
    }

    float acc[8];
    #pragma unroll
    for (int e = 0; e < 8; e++){
        float a = 0.f;
        #pragma unroll
        for (int dd = 0; dd < 3; dd++){
            const int d = dd - 1;
            int B1 = b0 + c1 + 32*e + d;
            bool ok = fvA[dd] && ((unsigned)B1 < (unsigned)L);
            float wd = ok ? rl[c1 + 32*e + d + 1] : 0.f;
            a += wd * S[dd][e];
        }
        acc[e] = a;
    }
    float* o = F1 + (size_t)A*L + b0 + c1;
    #pragma unroll
    for (int e = 0; e < 8; e++) o[32*e] = acc[e];
}

// -------- fuse2 (3-tap, transposed-flat wrap) + mask + softmax, vectorized -------
__global__ __launch_bounds__(256) void fsoft_kernel(const float* __restrict__ F1,
                                                    const float* __restrict__ mmv,
                                                    bf16* __restrict__ attn){
    int A = blockIdx.x, t = threadIdx.x;
    int i = A >> 6, j = A & 63;
    bool pok = A < L-1, mok = A > 0;
    int rowp = (i < 63) ? A + 64 : j + 1;
    int rowm = (i > 0)  ? A - 64 : 63*64 + j - 1;
    const float* FA = F1 + (size_t)A*L;
    const float* FP = F1 + (size_t)rowp*L;
    const float* FM = F1 + (size_t)rowm*L;

    float z[16]; float mx = -1e30f;
    #pragma unroll
    for (int it = 0; it < 4; it++){
        int b0 = (it*256 + t)*4;
        int p = b0 >> 6, q0 = b0 & 63;
        f32x4 v  = *(const f32x4*)(FA + b0);
        f32x4 mv = *(const f32x4*)(mmv + b0);
        f32x4 tp, tm;
        if (p < 63) tp = ((const uf4*)(FP + b0 + 64))->v;
        else        tp = ((const uf4*)(FP + q0 + 1))->v;
        if (p > 0)  tm = ((const uf4*)(FM + b0 - 64))->v;
        else        tm = ((const uf4*)(FM + 63*64 + q0 - 1))->v;
        #pragma unroll
        for (int e = 0; e < 4; e++){
            int Bq = b0 + e;
            float val = v[e];
            if (pok && Bq < L-1) val += tp[e];
            if (mok && Bq > 0)   val += tm[e];
            val = val * mv[e] * 10.f;
            z[it*4+e] = val; mx = fmaxf(mx, val);
        }
    }
    __shared__ float red[4];
    #pragma unroll
    for (int o = 32; o > 0; o >>= 1) mx = fmaxf(mx, __shfl_down(mx, o));
    if ((t & 63) == 0) red[t >> 6] = mx;
    __syncthreads();
    mx = fmaxf(fmaxf(red[0], red[1]), fmaxf(red[2], red[3]));
    float sm = 0.f;
    #pragma unroll
    for (int it = 0; it < 16; it++){ z[it] = __expf(z[it] - mx); sm += z[it]; }
    #pragma unroll
    for (int o = 32; o > 0; o >>= 1) sm += __shfl_down(sm, o);
    __syncthreads();
    if ((t & 63) == 0) red[t >> 6] = sm;
    __syncthreads();
    sm = red[0] + red[1] + red[2] + red[3];
    float inv = 1.f / sm;
    bf16* aA = attn + (size_t)A*L;
    #pragma unroll
    for (int it = 0; it < 4; it++){
        int b0 = (it*256 + t)*4;
        f32x4 mv = *(const f32x4*)(mmv + b0);
        short sv[4];
        #pragma unroll
        for (int e = 0; e < 4; e++)
            sv[e] = f2bf_s(z[it*4+e] * inv * mv[e]);
        *(short4v*)(aA + b0) = *(short4v*)&sv[0];
    }
}

// ---------------- v4: materialize 4 parity V matrices, 9 shared tap-rows ---------
__global__ __launch_bounds__(256) void v4_kernel(const bf16* __restrict__ attn,
                                                 bf16* __restrict__ V4){
    int t = threadIdx.x;
    int k0 = (blockIdx.x*256 + t)*8;
    int m  = blockIdx.y;
    int X = m >> 6, Yv = m & 63, P = k0 >> 6, Q0 = k0 & 63;

    const int del[9] = {0, 64, -64, 1, -1, 65, 63, -65, -63};
    float e8[9][8];
    #pragma unroll
    for (int r = 0; r < 9; r++){
        const int d = del[r];
        const bf16* base = attn + (size_t)(m - d)*L + (k0 - d);
        if ((d & 1) == 0){
            uint w[4];
            *(uint4*)w = ((const uu4*)base)->v;
            #pragma unroll
            for (int j = 0; j < 8; j++)
                e8[r][j] = u2f((j & 1) ? (w[j>>1] & 0xffff0000u) : (w[j>>1] << 16));
        } else {
            uint w[5];
            *(uint4*)w = ((const uu4*)(base - 1))->v;
            w[4] = *(const uint*)(base + 7);
            #pragma unroll
            for (int j = 0; j < 8; j++){
                int h = j + 1;
                e8[r][j] = u2f((h & 1) ? (w[h>>1] & 0xffff0000u) : (w[h>>1] << 16));
            }
        }
    }

    #pragma unroll
    for (int par = 0; par < 4; par++){
        const int sx = 1 - 2*(par >> 1), sy = 1 - 2*(par & 1);
        const int i2 = (sx > 0) ? 1 : 2;
        const int i3 = (sy > 0) ? 3 : 4;
        const int i4 = (sx > 0) ? ((sy > 0) ? 5 : 6) : ((sy > 0) ? 8 : 7);
        bool c2 = (unsigned)(P - sx) < 64u;
        bool m2 = ((unsigned)(X - sx) < 64u) && c2;
        bool r3 = (unsigned)(Yv - sy) < 64u;
        bool m4 = m2 && r3;
        uint ow[4];
        #pragma unroll
        for (int w = 0; w < 4; w++){
            float vv[2];
            #pragma unroll
            for (int h = 0; h < 2; h++){
                int j = 2*w + h;
                bool qk = (unsigned)(Q0 + j - sy) < 64u;
                float v = e8[0][j]
                        + (m2 ? e8[i2][j] : 0.f)
                        + ((r3 && qk) ? e8[i3][j] : 0.f)
                        + ((m4 && qk) ? e8[i4][j] : 0.f);
                vv[h] = v;
            }
            ow[w] = f2bf_u(vv[0]) | (f2bf_u(vv[1]) << 16);
        }
        *(uint4*)(V4 + (size_t)par*SLL + (size_t)m*L + k0) = *(uint4*)ow;
    }
}

// ---------------- paste GEMM: out = 0.25 * V4_par @ bparT_par^T ------------------
// R2-measured structure: M64 tile, single-buffered, grid (64,4) = 1 block/CU.
__global__ __launch_bounds__(256) void gemm_paste(
        const bf16* __restrict__ V4, const bf16* __restrict__ bparT,
        float* __restrict__ out, int batch){
    __shared__ __align__(16) bf16 Ab[64][72];
    __shared__ __align__(16) bf16 Bb[192][72];
    int t = threadIdx.x;
    int par = blockIdx.y;
    int m0 = blockIdx.x * 64;
    const bf16* Am = V4    + (size_t)par*SLL;
    const bf16* Bm = bparT + (size_t)par*C*L;
    int wv = t >> 6, lane = t & 63, lr = lane & 15, lq = lane >> 4;
    f32x4 acc[4][3] = {};

    for (int kk = 0; kk < 64; kk++){
        int k0 = kk * 64;
        __syncthreads();
        #pragma unroll
        for (int r = 0; r < 2; r++){
            int e = r*256 + t; int row = e >> 3, kc = e & 7;
            *(uint4*)&Ab[row][kc*8] = *(const uint4*)(Am + (size_t)(m0+row)*L + k0 + kc*8);
        }
        #pragma unroll
        for (int r = 0; r < 6; r++){
            int e = r*256 + t; int c2 = e >> 3, kc = e & 7;
            *(uint4*)&Bb[c2][kc*8] = *(const uint4*)(Bm + (size_t)c2*L + k0 + kc*8);
        }
        __syncthreads();
        #pragma unroll
        for (int kk2 = 0; kk2 < 2; kk2++){
            bf16x8 a[4], bfr[3];
            #pragma unroll
            for (int mt = 0; mt < 4; mt++)
                a[mt] = *(bf16x8*)&Ab[mt*16 + lr][kk2*32 + lq*8];
            #pragma unroll
            for (int nt = 0; nt < 3; nt++)
                bfr[nt] = *(bf16x8*)&Bb[wv*48 + nt*16 + lr][kk2*32 + lq*8];
            #pragma unroll
            for (int mt = 0; mt < 4; mt++)
              #pragma unroll
              for (int nt = 0; nt < 3; nt++)
                acc[mt][nt] = __builtin_amdgcn_mfma_f32_16x16x32_bf16(a[mt], bfr[nt], acc[mt][nt], 0,0,0);
        }
    }
    #pragma unroll
    for (int mt = 0; mt < 4; mt++)
      #pragma unroll
      for (int nt = 0; nt < 3; nt++)
        #pragma unroll
        for (int r = 0; r < 4; r++){
            int m = m0 + mt*16 + lq*4 + r;
            int X = m >> 6, Yv = m & 63;
            int dx = par >> 1, dy = par & 1;
            int x = 2*X + dx, y = 2*Yv + dy, c2 = wv*48 + nt*16 + lr;
            out[(size_t)((batch*HF + x)*HF + y)*C + c2] = 0.25f * acc[mt][nt][r];
        }
}

// ---------------- host ----------------
extern "C" void kernel_launch(void* const* d_in, const int* in_sizes, int n_in,
                              void* d_out, int out_size, void* d_ws, size_t ws_size,
                              hipStream_t stream){
    const float* f    = (const float*)d_in[0];
    const float* b    = (const float*)d_in[1];
    const float* mask = (const float*)d_in[2];
    float* out = (float*)d_out;
    char* ws = (char*)d_ws;

    constexpr size_t off_G     = 1179648ull;               // 64 MB, 1.125 MB guards
    constexpr size_t off_F1    = 69468160ull;              // 64 MB
    constexpr size_t off_attn  = 137232384ull;             // 32 MB, ~640 KB guards
    constexpr size_t off_bparT = 171442176ull;             // 6.29 MB
    constexpr size_t off_ss    = 177733632ull;
    constexpr size_t off_rn    = 177750016ull;
    constexpr size_t off_mmv   = 177766656ull;

    float* G    = (float*)(ws + off_G);
    float* F1   = (float*)(ws + off_F1);
    bf16*  attn = (bf16*) (ws + off_attn);
    bf16*  V4   = (bf16*) (ws);                            // 128 MB, overlays G+F1 (dead)
    bf16*  bpar = (bf16*) (ws + off_F1);                   // alias: dead before F1 written
    bf16*  fdh  = (bf16*) (ws + off_attn);                 // alias: dead before attn written
    bf16*  fdl  = (bf16*) (ws + off_attn + 1572864ull);
    bf16*  bdh  = (bf16*) (ws + off_attn + 3145728ull);
    bf16*  bdl  = (bf16*) (ws + off_attn + 4718592ull);
    bf16*  bparT= (bf16*) (ws + off_bparT);
    float* ss    = (float*)(ws + off_ss);
    float* rnorm = (float*)(ws + off_rn) + 16;
    float* mmv   = (float*)(ws + off_mmv);

    for (int batch = 0; batch < 2; batch++){
        prep_kernel  <<<dim3(4096),    dim3(192), 0, stream>>>(f, b, fdh, fdl, bdh, bdl, bpar, ss, batch);
        normmm_kernel<<<dim3(16),      dim3(256), 0, stream>>>(mask, ss, rnorm, mmv);
        repack_kernel<<<dim3(3,64,4),  dim3(256), 0, stream>>>(bpar, bparT);
        gemm_g       <<<dim3(32,32),   dim3(256), 0, stream>>>(fdh, fdl, bdh, bdl, G);
        s1f_kernel   <<<dim3(16,512),  dim3(256), 0, stream>>>(G, rnorm, F1);
        fsoft_kernel <<<dim3(4096),    dim3(256), 0, stream>>>(F1, mmv, attn);
        v4_kernel    <<<dim3(2,4096),  dim3(256), 0, stream>>>(attn, V4);
        gemm_paste   <<<dim3(64,4),    dim3(256), 0, stream>>>(V4, bparT, out, batch);
    }
}